// Round 2
// baseline (3163.078 us; speedup 1.0000x reference)
//
#include <hip/hip_runtime.h>
#include <hip/hip_bf16.h>

typedef unsigned short u16;
typedef unsigned int   u32;

using bf16x8 = __attribute__((ext_vector_type(8))) short;
using f32x4  = __attribute__((ext_vector_type(4))) float;

constexpr int S = 4096, DIM = 4096, H = 32, HL = 8, D = 128;
constexpr int NQKV = (H + 2 * HL) * D;   // 6144
constexpr int TB = S / 8;                // 512 blocks of 8 tokens
constexpr int KL = 108;                  // 4 sink + 4 window + 100 heavy
constexpr float NEGF = -1e30f;
constexpr float SCALE = 0.08838834764831845f;  // 1/sqrt(128)

__device__ inline u16 f2bf(float f) {
  __hip_bfloat16 h = __float2bfloat16(f);
  return __builtin_bit_cast(u16, h);
}
__device__ inline float bflo(u32 u) { return __builtin_bit_cast(float, u << 16); }
__device__ inline float bfhi(u32 u) { return __builtin_bit_cast(float, u & 0xFFFF0000u); }

// RNE split: returns bf16 hi, residual in rest (exact in f32)
__device__ inline u16 rne_hi(float f, float& rest) {
  u32 b = __builtin_bit_cast(u32, f);
  u32 h = (b + 0x7FFFu + ((b >> 16) & 1u)) >> 16;
  rest = f - __builtin_bit_cast(float, h << 16);
  return (u16)h;
}
__device__ inline u16 rne16(float f) {
  u32 b = __builtin_bit_cast(u32, f);
  return (u16)((b + 0x7FFFu + ((b >> 16) & 1u)) >> 16);
}

// ============ split-4 GEMM: C = A[M,K] * B[N,K]^T, near-f32 accuracy ========
// A,B f32 in global; staged as (hi,lo) bf16 pairs; 4 MFMA terms per frag pair.
// 128x128 tile, BK=32, 256 threads (4 waves 2x2), wave = 64x64 (4x4 MFMA).
__global__ __launch_bounds__(256) void gemm_split4(
    const float* __restrict__ Ap, const float* __restrict__ Bp,
    float* __restrict__ C, int M, int N, int K) {
  __shared__ u16 Ah[128][40];  // row stride 80B = 5*16B: b128-aligned, <=2-way banks
  __shared__ u16 Al[128][40];
  __shared__ u16 Bh[128][40];
  __shared__ u16 Bl[128][40];
  const int tid = threadIdx.x;
  const int lane = tid & 63;
  const int w = tid >> 6;
  const int wm = w >> 1, wn = w & 1;
  const int m0 = blockIdx.y * 128, n0 = blockIdx.x * 128;
  const int l15 = lane & 15, g = lane >> 4;

  f32x4 acc[4][4];
#pragma unroll
  for (int i = 0; i < 4; ++i)
#pragma unroll
    for (int j = 0; j < 4; ++j) acc[i][j] = {0.f, 0.f, 0.f, 0.f};

  for (int k0 = 0; k0 < K; k0 += 32) {
#pragma unroll
    for (int it = 0; it < 2; ++it) {
      const int idx = (it * 256 + tid) * 8;
      const int rr = idx >> 5, cc = idx & 31;
      {
        const float* sp = Ap + (size_t)(m0 + rr) * K + k0 + cc;
        uint4 ph, pl;
        float r0, r1;
        u16 h0, h1;
        h0 = rne_hi(sp[0], r0); h1 = rne_hi(sp[1], r1);
        ph.x = h0 | ((u32)h1 << 16); pl.x = rne16(r0) | ((u32)rne16(r1) << 16);
        h0 = rne_hi(sp[2], r0); h1 = rne_hi(sp[3], r1);
        ph.y = h0 | ((u32)h1 << 16); pl.y = rne16(r0) | ((u32)rne16(r1) << 16);
        h0 = rne_hi(sp[4], r0); h1 = rne_hi(sp[5], r1);
        ph.z = h0 | ((u32)h1 << 16); pl.z = rne16(r0) | ((u32)rne16(r1) << 16);
        h0 = rne_hi(sp[6], r0); h1 = rne_hi(sp[7], r1);
        ph.w = h0 | ((u32)h1 << 16); pl.w = rne16(r0) | ((u32)rne16(r1) << 16);
        *(uint4*)&Ah[rr][cc] = ph;
        *(uint4*)&Al[rr][cc] = pl;
      }
      {
        const float* sp = Bp + (size_t)(n0 + rr) * K + k0 + cc;
        uint4 ph, pl;
        float r0, r1;
        u16 h0, h1;
        h0 = rne_hi(sp[0], r0); h1 = rne_hi(sp[1], r1);
        ph.x = h0 | ((u32)h1 << 16); pl.x = rne16(r0) | ((u32)rne16(r1) << 16);
        h0 = rne_hi(sp[2], r0); h1 = rne_hi(sp[3], r1);
        ph.y = h0 | ((u32)h1 << 16); pl.y = rne16(r0) | ((u32)rne16(r1) << 16);
        h0 = rne_hi(sp[4], r0); h1 = rne_hi(sp[5], r1);
        ph.z = h0 | ((u32)h1 << 16); pl.z = rne16(r0) | ((u32)rne16(r1) << 16);
        h0 = rne_hi(sp[6], r0); h1 = rne_hi(sp[7], r1);
        ph.w = h0 | ((u32)h1 << 16); pl.w = rne16(r0) | ((u32)rne16(r1) << 16);
        *(uint4*)&Bh[rr][cc] = ph;
        *(uint4*)&Bl[rr][cc] = pl;
      }
    }
    __syncthreads();
    bf16x8 afh[4], afl[4], bfh[4], bfl[4];
#pragma unroll
    for (int i = 0; i < 4; ++i) {
      afh[i] = *(const bf16x8*)&Ah[wm * 64 + i * 16 + l15][g * 8];
      afl[i] = *(const bf16x8*)&Al[wm * 64 + i * 16 + l15][g * 8];
    }
#pragma unroll
    for (int j = 0; j < 4; ++j) {
      bfh[j] = *(const bf16x8*)&Bh[wn * 64 + j * 16 + l15][g * 8];
      bfl[j] = *(const bf16x8*)&Bl[wn * 64 + j * 16 + l15][g * 8];
    }
#pragma unroll
    for (int i = 0; i < 4; ++i)
#pragma unroll
      for (int j = 0; j < 4; ++j) {
        acc[i][j] = __builtin_amdgcn_mfma_f32_16x16x32_bf16(afl[i], bfl[j], acc[i][j], 0, 0, 0);
        acc[i][j] = __builtin_amdgcn_mfma_f32_16x16x32_bf16(afl[i], bfh[j], acc[i][j], 0, 0, 0);
        acc[i][j] = __builtin_amdgcn_mfma_f32_16x16x32_bf16(afh[i], bfl[j], acc[i][j], 0, 0, 0);
        acc[i][j] = __builtin_amdgcn_mfma_f32_16x16x32_bf16(afh[i], bfh[j], acc[i][j], 0, 0, 0);
      }
    __syncthreads();
  }
  // C/D layout: col = lane&15, row = (lane>>4)*4 + reg   [verified m89/m91]
#pragma unroll
  for (int i = 0; i < 4; ++i)
#pragma unroll
    for (int j = 0; j < 4; ++j)
#pragma unroll
      for (int rg = 0; rg < 4; ++rg) {
        int row = m0 + wm * 64 + i * 16 + g * 4 + rg;
        int col = n0 + wn * 64 + j * 16 + l15;
        C[(size_t)row * N + col] = acc[i][j][rg];
      }
}

// ============ bf16 GEMM for the output projection (A bf16, B f32) ===========
__global__ __launch_bounds__(256) void gemm_bt_bf16(
    const u16* __restrict__ Ap, const float* __restrict__ Bp,
    float* __restrict__ C, int M, int N, int K) {
  __shared__ u16 As[128][40];
  __shared__ u16 Bs[128][40];
  const int tid = threadIdx.x;
  const int lane = tid & 63;
  const int w = tid >> 6;
  const int wm = w >> 1, wn = w & 1;
  const int m0 = blockIdx.y * 128, n0 = blockIdx.x * 128;
  const int l15 = lane & 15, g = lane >> 4;

  f32x4 acc[4][4];
#pragma unroll
  for (int i = 0; i < 4; ++i)
#pragma unroll
    for (int j = 0; j < 4; ++j) acc[i][j] = {0.f, 0.f, 0.f, 0.f};

  for (int k0 = 0; k0 < K; k0 += 32) {
#pragma unroll
    for (int it = 0; it < 2; ++it) {
      const int idx = (it * 256 + tid) * 8;
      const int rr = idx >> 5, cc = idx & 31;
      *(uint4*)&As[rr][cc] = *(const uint4*)(Ap + (size_t)(m0 + rr) * K + k0 + cc);
      const float* sp = Bp + (size_t)(n0 + rr) * K + k0 + cc;
      float4 v0 = *(const float4*)sp, v1 = *(const float4*)(sp + 4);
      uint4 pk;
      pk.x = rne16(v0.x) | ((u32)rne16(v0.y) << 16);
      pk.y = rne16(v0.z) | ((u32)rne16(v0.w) << 16);
      pk.z = rne16(v1.x) | ((u32)rne16(v1.y) << 16);
      pk.w = rne16(v1.z) | ((u32)rne16(v1.w) << 16);
      *(uint4*)&Bs[rr][cc] = pk;
    }
    __syncthreads();
    bf16x8 af[4], bfr[4];
#pragma unroll
    for (int i = 0; i < 4; ++i)
      af[i] = *(const bf16x8*)&As[wm * 64 + i * 16 + l15][g * 8];
#pragma unroll
    for (int j = 0; j < 4; ++j)
      bfr[j] = *(const bf16x8*)&Bs[wn * 64 + j * 16 + l15][g * 8];
#pragma unroll
    for (int i = 0; i < 4; ++i)
#pragma unroll
      for (int j = 0; j < 4; ++j)
        acc[i][j] = __builtin_amdgcn_mfma_f32_16x16x32_bf16(af[i], bfr[j], acc[i][j], 0, 0, 0);
    __syncthreads();
  }
#pragma unroll
  for (int i = 0; i < 4; ++i)
#pragma unroll
    for (int j = 0; j < 4; ++j)
#pragma unroll
      for (int rg = 0; rg < 4; ++rg) {
        int row = m0 + wm * 64 + i * 16 + g * 4 + rg;
        int col = n0 + wn * 64 + j * 16 + l15;
        C[(size_t)row * N + col] = acc[i][j][rg];
      }
}

// ---------------- RoPE on Q + q_mean partial sums ---------------------------
__global__ __launch_bounds__(256) void rope_q_kernel(
    const float* __restrict__ qkvf, const float* __restrict__ freqs,
    u16* __restrict__ qb, float* __restrict__ qmean) {
  const int h = blockIdx.y;
  const int s0 = blockIdx.x * 64;
  const int tid = threadIdx.x;
  const int d = tid & 127, half = tid >> 7;
  float sum = 0.f;
  for (int pp = half; pp < 64; pp += 2) {
    const int s = s0 + pp;
    const float* base = qkvf + (size_t)s * NQKV + h * D;
    float a = base[d & ~1], b = base[d | 1];
    float c = freqs[s * 128 + (d & ~1)], dd = freqs[s * 128 + (d | 1)];
    float o = (d & 1) ? (b * c + a * dd) : (a * c - b * dd);
    qb[((size_t)h * S + s) * D + d] = f2bf(o);
    sum += o;
  }
  __shared__ float red[256];
  red[tid] = sum;
  __syncthreads();
  if (half == 0) atomicAdd(&qmean[h * D + d], red[d] + red[128 + d]);
}

// ---------------- RoPE on K + block means + V cast --------------------------
__global__ __launch_bounds__(128) void rope_kv_kernel(
    const float* __restrict__ qkvf, const float* __restrict__ freqs,
    u16* __restrict__ kb, u16* __restrict__ vb, float* __restrict__ krep) {
  const int hl = blockIdx.y;
  const int t = blockIdx.x;  // token block 0..511
  const int d = threadIdx.x;
  float sum = 0.f;
#pragma unroll
  for (int pp = 0; pp < 8; ++pp) {
    const int s = t * 8 + pp;
    const float* base = qkvf + (size_t)s * NQKV + H * D + hl * D;
    float a = base[d & ~1], b = base[d | 1];
    float c = freqs[s * 128 + (d & ~1)], dd = freqs[s * 128 + (d | 1)];
    float o = (d & 1) ? (b * c + a * dd) : (a * c - b * dd);
    kb[((size_t)hl * S + s) * D + d] = f2bf(o);
    sum += o;
    vb[((size_t)hl * S + s) * D + d] = f2bf(base[HL * D + d]);  // v, no rope
  }
  krep[((size_t)t * HL + hl) * D + d] = sum * 0.125f;
}

// ---------------- scores + top-100 selection per head -----------------------
__global__ __launch_bounds__(512) void topk_kernel(
    const float* __restrict__ qmean, const float* __restrict__ krep,
    int* __restrict__ bidx) {
  const int h = blockIdx.x;
  const int t = threadIdx.x;  // block id 0..511
  __shared__ float qm[128];
  if (t < 128) qm[t] = qmean[h * 128 + t] * (1.f / 4096.f);
  __syncthreads();
  const float* kr = krep + ((size_t)t * HL + (h >> 2)) * 128;
  float s = 0.f;
#pragma unroll 8
  for (int d = 0; d < 128; ++d) s += qm[d] * kr[d];
  s *= SCALE;
  if (t < 4 || t >= 508) s = NEGF;  // sink + window masked out of top-k
  if (t < 4) {
    bidx[h * KL + t] = t;            // sink blocks 0..3
    bidx[h * KL + 4 + t] = 508 + t;  // window blocks 508..511
  }
  __shared__ float wv[8];
  __shared__ int wi[8];
  __shared__ int bestsh;
  for (int iter = 0; iter < 100; ++iter) {
    float v = s;
    int idx = t;
#pragma unroll
    for (int off = 1; off < 64; off <<= 1) {
      float ov = __shfl_xor(v, off, 64);
      int oi = __shfl_xor(idx, off, 64);
      if (ov > v || (ov == v && oi < idx)) { v = ov; idx = oi; }
    }
    if ((t & 63) == 0) { wv[t >> 6] = v; wi[t >> 6] = idx; }
    __syncthreads();
    if (t == 0) {
      float bv = wv[0];
      int bi = wi[0];
#pragma unroll
      for (int u = 1; u < 8; ++u)
        if (wv[u] > bv || (wv[u] == bv && wi[u] < bi)) { bv = wv[u]; bi = wi[u]; }
      bestsh = bi;
      bidx[h * KL + 8 + iter] = bi;
    }
    __syncthreads();
    if (t == bestsh) s = NEGF;
  }
}

// ---------------- flash attention over selected blocks ----------------------
// grid (S/64, H); 256 thr = 4 waves; wave w owns rows w*16..w*16+15;
// lane = dp*16 + r : r = local row, dp = d-quarter (32 d each).
__global__ __launch_bounds__(256) void attn_kernel(
    const u16* __restrict__ qb, const u16* __restrict__ kb,
    const u16* __restrict__ vb, const int* __restrict__ bidx,
    u16* __restrict__ attno) {
  const int h = blockIdx.y;
  const int q0 = blockIdx.x * 64;
  const int hl = h >> 2;
  const int tid = threadIdx.x;
  const int w = tid >> 6, lane = tid & 63;
  const int r = lane & 15, dp = lane >> 4;
  const int sq = q0 + w * 16 + r;

  __shared__ u16 Ks[8][128];
  __shared__ u16 Vs[8][128];

  float q[32], o[32];
  {
    const u16* qp = qb + ((size_t)h * S + sq) * D + dp * 32;
#pragma unroll
    for (int j0 = 0; j0 < 32; j0 += 8) {
      uint4 u = *(const uint4*)(qp + j0);
      q[j0 + 0] = bflo(u.x); q[j0 + 1] = bfhi(u.x);
      q[j0 + 2] = bflo(u.y); q[j0 + 3] = bfhi(u.y);
      q[j0 + 4] = bflo(u.z); q[j0 + 5] = bfhi(u.z);
      q[j0 + 6] = bflo(u.w); q[j0 + 7] = bfhi(u.w);
    }
  }
#pragma unroll
  for (int j = 0; j < 32; ++j) o[j] = 0.f;
  float m = NEGF, l = 0.f;

  for (int it = 0; it < KL; ++it) {
    const int blk = bidx[h * KL + it];
    {
      const int tt = tid & 127;
      const int tok = tt >> 4, dc = (tt & 15) * 8;
      size_t src = ((size_t)hl * S + blk * 8 + tok) * D + dc;
      if (tid < 128) *(uint4*)&Ks[tok][dc] = *(const uint4*)(kb + src);
      else           *(uint4*)&Vs[tok][dc] = *(const uint4*)(vb + src);
    }
    __syncthreads();
    float sc[8];
#pragma unroll
    for (int tk = 0; tk < 8; ++tk) {
      const u16* kp = &Ks[tk][dp * 32];
      float p = 0.f;
#pragma unroll
      for (int j0 = 0; j0 < 32; j0 += 8) {
        uint4 u = *(const uint4*)(kp + j0);
        p += q[j0 + 0] * bflo(u.x) + q[j0 + 1] * bfhi(u.x)
           + q[j0 + 2] * bflo(u.y) + q[j0 + 3] * bfhi(u.y)
           + q[j0 + 4] * bflo(u.z) + q[j0 + 5] * bfhi(u.z)
           + q[j0 + 6] * bflo(u.w) + q[j0 + 7] * bfhi(u.w);
      }
      p += __shfl_xor(p, 16, 64);  // reduce over dp quarters
      p += __shfl_xor(p, 32, 64);
      const int tok = blk * 8 + tk;
      sc[tk] = (tok <= sq) ? p * SCALE : NEGF;  // causal mask
    }
    float mc = sc[0];
#pragma unroll
    for (int tk = 1; tk < 8; ++tk) mc = fmaxf(mc, sc[tk]);
    const float mnew = fmaxf(m, mc);
    const float alpha = __expf(m - mnew);
    float ps[8], sl = 0.f;
#pragma unroll
    for (int tk = 0; tk < 8; ++tk) { ps[tk] = __expf(sc[tk] - mnew); sl += ps[tk]; }
    l = l * alpha + sl;
    m = mnew;
#pragma unroll
    for (int j = 0; j < 32; ++j) o[j] *= alpha;
#pragma unroll
    for (int tk = 0; tk < 8; ++tk) {
      const u16* vp = &Vs[tk][dp * 32];
      const float pt = ps[tk];
#pragma unroll
      for (int j0 = 0; j0 < 32; j0 += 8) {
        uint4 u = *(const uint4*)(vp + j0);
        o[j0 + 0] += pt * bflo(u.x); o[j0 + 1] += pt * bfhi(u.x);
        o[j0 + 2] += pt * bflo(u.y); o[j0 + 3] += pt * bfhi(u.y);
        o[j0 + 4] += pt * bflo(u.z); o[j0 + 5] += pt * bfhi(u.z);
        o[j0 + 6] += pt * bflo(u.w); o[j0 + 7] += pt * bfhi(u.w);
      }
    }
    __syncthreads();
  }
  const float inv = 1.f / l;
  u16* op = attno + (size_t)sq * DIM + h * D + dp * 32;
#pragma unroll
  for (int j0 = 0; j0 < 32; j0 += 8) {
    uint4 u;
    u.x = f2bf(o[j0 + 0] * inv) | ((u32)f2bf(o[j0 + 1] * inv) << 16);
    u.y = f2bf(o[j0 + 2] * inv) | ((u32)f2bf(o[j0 + 3] * inv) << 16);
    u.z = f2bf(o[j0 + 4] * inv) | ((u32)f2bf(o[j0 + 5] * inv) << 16);
    u.w = f2bf(o[j0 + 6] * inv) | ((u32)f2bf(o[j0 + 7] * inv) << 16);
    *(uint4*)(op + j0) = u;
  }
}

extern "C" void kernel_launch(void* const* d_in, const int* in_sizes, int n_in,
                              void* d_out, int out_size, void* d_ws, size_t ws_size,
                              hipStream_t stream) {
  const float* x     = (const float*)d_in[0];  // (1,4096,4096)
  const float* freqs = (const float*)d_in[1];  // (4096,64,2)
  const float* wqkv  = (const float*)d_in[2];  // (6144,4096)
  const float* wo    = (const float*)d_in[3];  // (4096,4096)
  float* out = (float*)d_out;                  // (1,4096,4096) f32

  char* p = (char*)d_ws;
  auto alloc = [&](size_t bytes) {
    char* r = p;
    p += (bytes + 255) & ~(size_t)255;
    return r;
  };
  float* qkvf  = (float*)alloc((size_t)S * NQKV * 4);   // 100.7 MB
  u16*   qb    = (u16*)alloc((size_t)H * S * D * 2);    // 32 MB (H,S,D)
  u16*   kb    = (u16*)alloc((size_t)HL * S * D * 2);   // 8 MB (HL,S,D)
  u16*   vb    = (u16*)alloc((size_t)HL * S * D * 2);   // 8 MB
  float* krep  = (float*)alloc((size_t)TB * HL * D * 4);// 2 MB (TB,HL,D)
  float* qmean = (float*)alloc((size_t)H * D * 4);
  int*   bidx  = (int*)alloc((size_t)H * KL * 4);
  u16*   attno = (u16*)alloc((size_t)S * DIM * 2);      // 32 MB (S, H*D)

  hipMemsetAsync(qmean, 0, (size_t)H * D * 4, stream);

  // near-f32 qkv: selection path (q_mean / k_rep) must match f32 reference
  gemm_split4<<<dim3(NQKV / 128, S / 128), 256, 0, stream>>>(
      x, wqkv, qkvf, S, NQKV, DIM);
  rope_q_kernel<<<dim3(S / 64, H), 256, 0, stream>>>(qkvf, freqs, qb, qmean);
  rope_kv_kernel<<<dim3(TB, HL), 128, 0, stream>>>(qkvf, freqs, kb, vb, krep);
  topk_kernel<<<H, 512, 0, stream>>>(qmean, krep, bidx);
  attn_kernel<<<dim3(S / 64, H), 256, 0, stream>>>(qb, kb, vb, bidx, attno);
  gemm_bt_bf16<<<dim3(DIM / 128, S / 128), 256, 0, stream>>>(
      attno, wo, out, S, DIM, DIM);
}

// Round 3
// 1718.051 us; speedup vs baseline: 1.8411x; 1.8411x over previous
//
#include <hip/hip_runtime.h>
#include <hip/hip_bf16.h>

typedef unsigned short u16;
typedef unsigned int   u32;

using bf16x8 = __attribute__((ext_vector_type(8))) short;
using f32x4  = __attribute__((ext_vector_type(4))) float;

constexpr int S = 4096, DIM = 4096, H = 32, HL = 8, D = 128;
constexpr int NQKV = (H + 2 * HL) * D;   // 6144
constexpr int TB = S / 8;                // 512 blocks of 8 tokens
constexpr int KL = 108;                  // 4 sink + 4 window + 100 heavy
constexpr float NEGF = -1e30f;
constexpr float SCALE = 0.08838834764831845f;  // 1/sqrt(128)

__device__ inline float bflo(u32 u) { return __builtin_bit_cast(float, u << 16); }
__device__ inline float bfhi(u32 u) { return __builtin_bit_cast(float, u & 0xFFFF0000u); }
__device__ inline u16 rne16(float f) {
  u32 b = __builtin_bit_cast(u32, f);
  return (u16)((b + 0x7FFFu + ((b >> 16) & 1u)) >> 16);
}
// trunc-hi split: hi = truncate(f), lo = rne(f - hi).  hi-bias captured exactly by lo.
__device__ inline void split2(float f, u16& hi, u16& lo) {
  u32 b = __builtin_bit_cast(u32, f);
  hi = (u16)(b >> 16);
  float r = f - __builtin_bit_cast(float, b & 0xFFFF0000u);
  lo = rne16(r);
}

// ============ generic bf16 GEMM: C[M,N] = A[M,K] * B[N,K]^T =================
// f32 sources converted to bf16 during staging; 128x128 tile, BK=32.
template <bool ABF16, bool OBF16>
__global__ __launch_bounds__(256) void gemm_conv(
    const void* __restrict__ Ap, const float* __restrict__ Bp,
    void* __restrict__ Cp, int M, int N, int K) {
  __shared__ u16 As[128][40];
  __shared__ u16 Bs[128][40];
  const int tid = threadIdx.x;
  const int lane = tid & 63;
  const int w = tid >> 6;
  const int wm = w >> 1, wn = w & 1;
  const int m0 = blockIdx.y * 128, n0 = blockIdx.x * 128;
  const int l15 = lane & 15, g = lane >> 4;

  f32x4 acc[4][4];
#pragma unroll
  for (int i = 0; i < 4; ++i)
#pragma unroll
    for (int j = 0; j < 4; ++j) acc[i][j] = {0.f, 0.f, 0.f, 0.f};

  for (int k0 = 0; k0 < K; k0 += 32) {
#pragma unroll
    for (int it = 0; it < 2; ++it) {
      const int idx = (it * 256 + tid) * 8;
      const int rr = idx >> 5, cc = idx & 31;
      if constexpr (ABF16) {
        const u16* A = (const u16*)Ap;
        *(uint4*)&As[rr][cc] = *(const uint4*)(A + (size_t)(m0 + rr) * K + k0 + cc);
      } else {
        const float* A = (const float*)Ap;
        const float* sp = A + (size_t)(m0 + rr) * K + k0 + cc;
        float4 v0 = *(const float4*)sp, v1 = *(const float4*)(sp + 4);
        uint4 pk;
        pk.x = rne16(v0.x) | ((u32)rne16(v0.y) << 16);
        pk.y = rne16(v0.z) | ((u32)rne16(v0.w) << 16);
        pk.z = rne16(v1.x) | ((u32)rne16(v1.y) << 16);
        pk.w = rne16(v1.z) | ((u32)rne16(v1.w) << 16);
        *(uint4*)&As[rr][cc] = pk;
      }
      {
        const float* sp = Bp + (size_t)(n0 + rr) * K + k0 + cc;
        float4 v0 = *(const float4*)sp, v1 = *(const float4*)(sp + 4);
        uint4 pk;
        pk.x = rne16(v0.x) | ((u32)rne16(v0.y) << 16);
        pk.y = rne16(v0.z) | ((u32)rne16(v0.w) << 16);
        pk.z = rne16(v1.x) | ((u32)rne16(v1.y) << 16);
        pk.w = rne16(v1.z) | ((u32)rne16(v1.w) << 16);
        *(uint4*)&Bs[rr][cc] = pk;
      }
    }
    __syncthreads();
    bf16x8 af[4], bfr[4];
#pragma unroll
    for (int i = 0; i < 4; ++i)
      af[i] = *(const bf16x8*)&As[wm * 64 + i * 16 + l15][g * 8];
#pragma unroll
    for (int j = 0; j < 4; ++j)
      bfr[j] = *(const bf16x8*)&Bs[wn * 64 + j * 16 + l15][g * 8];
#pragma unroll
    for (int i = 0; i < 4; ++i)
#pragma unroll
      for (int j = 0; j < 4; ++j)
        acc[i][j] = __builtin_amdgcn_mfma_f32_16x16x32_bf16(af[i], bfr[j], acc[i][j], 0, 0, 0);
    __syncthreads();
  }
  // C/D layout: col = lane&15, row = (lane>>4)*4 + reg   [verified m89/m91]
#pragma unroll
  for (int i = 0; i < 4; ++i)
#pragma unroll
    for (int j = 0; j < 4; ++j)
#pragma unroll
      for (int rg = 0; rg < 4; ++rg) {
        int row = m0 + wm * 64 + i * 16 + g * 4 + rg;
        int col = n0 + wn * 64 + j * 16 + l15;
        if constexpr (OBF16)
          ((u16*)Cp)[(size_t)row * N + col] = rne16(acc[i][j][rg]);
        else
          ((float*)Cp)[(size_t)row * N + col] = acc[i][j][rg];
      }
}

// ============ split-3 GEMM (near-f32): for the K-head precise path ==========
__global__ __launch_bounds__(256) void gemm_split3(
    const float* __restrict__ Ap, const float* __restrict__ Bp,
    float* __restrict__ C, int M, int N, int K) {
  __shared__ u16 Ah[128][40];
  __shared__ u16 Al[128][40];
  __shared__ u16 Bh[128][40];
  __shared__ u16 Bl[128][40];
  const int tid = threadIdx.x;
  const int lane = tid & 63;
  const int w = tid >> 6;
  const int wm = w >> 1, wn = w & 1;
  const int m0 = blockIdx.y * 128, n0 = blockIdx.x * 128;
  const int l15 = lane & 15, g = lane >> 4;

  f32x4 acc[4][4];
#pragma unroll
  for (int i = 0; i < 4; ++i)
#pragma unroll
    for (int j = 0; j < 4; ++j) acc[i][j] = {0.f, 0.f, 0.f, 0.f};

  for (int k0 = 0; k0 < K; k0 += 32) {
#pragma unroll
    for (int it = 0; it < 2; ++it) {
      const int idx = (it * 256 + tid) * 8;
      const int rr = idx >> 5, cc = idx & 31;
      {
        const float* sp = Ap + (size_t)(m0 + rr) * K + k0 + cc;
        uint4 ph, pl;
        u16 h0, h1, l0, l1;
        split2(sp[0], h0, l0); split2(sp[1], h1, l1);
        ph.x = h0 | ((u32)h1 << 16); pl.x = l0 | ((u32)l1 << 16);
        split2(sp[2], h0, l0); split2(sp[3], h1, l1);
        ph.y = h0 | ((u32)h1 << 16); pl.y = l0 | ((u32)l1 << 16);
        split2(sp[4], h0, l0); split2(sp[5], h1, l1);
        ph.z = h0 | ((u32)h1 << 16); pl.z = l0 | ((u32)l1 << 16);
        split2(sp[6], h0, l0); split2(sp[7], h1, l1);
        ph.w = h0 | ((u32)h1 << 16); pl.w = l0 | ((u32)l1 << 16);
        *(uint4*)&Ah[rr][cc] = ph;
        *(uint4*)&Al[rr][cc] = pl;
      }
      {
        const float* sp = Bp + (size_t)(n0 + rr) * K + k0 + cc;
        uint4 ph, pl;
        u16 h0, h1, l0, l1;
        split2(sp[0], h0, l0); split2(sp[1], h1, l1);
        ph.x = h0 | ((u32)h1 << 16); pl.x = l0 | ((u32)l1 << 16);
        split2(sp[2], h0, l0); split2(sp[3], h1, l1);
        ph.y = h0 | ((u32)h1 << 16); pl.y = l0 | ((u32)l1 << 16);
        split2(sp[4], h0, l0); split2(sp[5], h1, l1);
        ph.z = h0 | ((u32)h1 << 16); pl.z = l0 | ((u32)l1 << 16);
        split2(sp[6], h0, l0); split2(sp[7], h1, l1);
        ph.w = h0 | ((u32)h1 << 16); pl.w = l0 | ((u32)l1 << 16);
        *(uint4*)&Bh[rr][cc] = ph;
        *(uint4*)&Bl[rr][cc] = pl;
      }
    }
    __syncthreads();
    bf16x8 afh[4], afl[4], bfh[4], bfl[4];
#pragma unroll
    for (int i = 0; i < 4; ++i) {
      afh[i] = *(const bf16x8*)&Ah[wm * 64 + i * 16 + l15][g * 8];
      afl[i] = *(const bf16x8*)&Al[wm * 64 + i * 16 + l15][g * 8];
    }
#pragma unroll
    for (int j = 0; j < 4; ++j) {
      bfh[j] = *(const bf16x8*)&Bh[wn * 64 + j * 16 + l15][g * 8];
      bfl[j] = *(const bf16x8*)&Bl[wn * 64 + j * 16 + l15][g * 8];
    }
#pragma unroll
    for (int i = 0; i < 4; ++i)
#pragma unroll
      for (int j = 0; j < 4; ++j) {
        acc[i][j] = __builtin_amdgcn_mfma_f32_16x16x32_bf16(afl[i], bfh[j], acc[i][j], 0, 0, 0);
        acc[i][j] = __builtin_amdgcn_mfma_f32_16x16x32_bf16(afh[i], bfl[j], acc[i][j], 0, 0, 0);
        acc[i][j] = __builtin_amdgcn_mfma_f32_16x16x32_bf16(afh[i], bfh[j], acc[i][j], 0, 0, 0);
      }
    __syncthreads();
  }
#pragma unroll
  for (int i = 0; i < 4; ++i)
#pragma unroll
    for (int j = 0; j < 4; ++j)
#pragma unroll
      for (int rg = 0; rg < 4; ++rg) {
        int row = m0 + wm * 64 + i * 16 + g * 4 + rg;
        int col = n0 + wn * 64 + j * 16 + l15;
        C[(size_t)row * N + col] = acc[i][j][rg];
      }
}

// ---------------- XC/XD: weighted token-sums of x (exact q_mean path) -------
// XC[i][d] = sum_s freqs[s][i][0] * x[s][d];  XD likewise with [1].
// grid (32 d-chunks, 2 i-chunks, 8 s-segs), block 128.
__global__ __launch_bounds__(128) void xcd_kernel(
    const float* __restrict__ x, const float* __restrict__ freqs,
    float* __restrict__ XC, float* __restrict__ XD) {
  const int d = blockIdx.x * 128 + threadIdx.x;
  const int i0 = blockIdx.y * 32;
  const int s0 = blockIdx.z * 512;
  float accC[32], accD[32];
#pragma unroll
  for (int ii = 0; ii < 32; ++ii) { accC[ii] = 0.f; accD[ii] = 0.f; }
  for (int s = s0; s < s0 + 512; ++s) {
    const float xv = x[(size_t)s * DIM + d];
    const float* fr = freqs + (size_t)s * 128 + i0 * 2;  // block-uniform -> s_loads
#pragma unroll
    for (int ii = 0; ii < 32; ++ii) {
      accC[ii] += fr[2 * ii] * xv;
      accD[ii] += fr[2 * ii + 1] * xv;
    }
  }
#pragma unroll
  for (int ii = 0; ii < 32; ++ii) {
    atomicAdd(&XC[(size_t)(i0 + ii) * DIM + d], accC[ii]);
    atomicAdd(&XD[(size_t)(i0 + ii) * DIM + d], accD[ii]);
  }
}

// ---------------- M1/M2: per-q-row dots with XC/XD --------------------------
// M1[r] = Wq[r]·XC[(r&127)>>1], M2[r] = Wq[r]·XD[(r&127)>>1]; r in [0,4096)
__global__ __launch_bounds__(256) void mrow_kernel(
    const float* __restrict__ wq, const float* __restrict__ XC,
    const float* __restrict__ XD, float* __restrict__ M1, float* __restrict__ M2) {
  const int r = blockIdx.x * 4 + (threadIdx.x >> 6);
  const int lane = threadIdx.x & 63;
  const int i = (r & 127) >> 1;
  const float* wr = wq + (size_t)r * DIM;
  const float* xc = XC + (size_t)i * DIM;
  const float* xd = XD + (size_t)i * DIM;
  float s1 = 0.f, s2 = 0.f;
  for (int k = lane; k < DIM; k += 64) {
    float wv = wr[k];
    s1 += wv * xc[k];
    s2 += wv * xd[k];
  }
#pragma unroll
  for (int off = 1; off < 64; off <<= 1) {
    s1 += __shfl_xor(s1, off, 64);
    s2 += __shfl_xor(s2, off, 64);
  }
  if (lane == 0) { M1[r] = s1; M2[r] = s2; }
}

// ---------------- RoPE on Q (bf16 in, bf16 out) -----------------------------
__global__ __launch_bounds__(256) void rope_q_kernel(
    const u16* __restrict__ qkvb, const float* __restrict__ freqs,
    u16* __restrict__ qb) {
  const int h = blockIdx.y;
  const int s0 = blockIdx.x * 64;
  const int tid = threadIdx.x;
  const int d = tid & 127, half = tid >> 7;
  for (int pp = half; pp < 64; pp += 2) {
    const int s = s0 + pp;
    u32 pr = *(const u32*)(qkvb + (size_t)s * NQKV + h * D + (d & ~1));
    float a = bflo(pr), b = bfhi(pr);
    float2 fc = *(const float2*)(freqs + (size_t)s * 128 + (d & ~1));
    float o = (d & 1) ? (b * fc.x + a * fc.y) : (a * fc.x - b * fc.y);
    qb[((size_t)h * S + s) * D + d] = rne16(o);
  }
}

// ---------------- RoPE on precise K + block means; V cast + transpose -------
__global__ __launch_bounds__(128) void rope_kv_kernel(
    const float* __restrict__ kf, const u16* __restrict__ qkvb,
    const float* __restrict__ freqs,
    u16* __restrict__ kb, u16* __restrict__ vbt, float* __restrict__ krep) {
  const int hl = blockIdx.y;
  const int t = blockIdx.x;  // token block 0..511
  const int d = threadIdx.x;
  float sum = 0.f;
  u16 vv[8];
#pragma unroll
  for (int pp = 0; pp < 8; ++pp) {
    const int s = t * 8 + pp;
    float2 kp = *(const float2*)(kf + (size_t)s * 1024 + hl * D + (d & ~1));
    float2 fc = *(const float2*)(freqs + (size_t)s * 128 + (d & ~1));
    float o = (d & 1) ? (kp.y * fc.x + kp.x * fc.y) : (kp.x * fc.x - kp.y * fc.y);
    kb[((size_t)hl * S + s) * D + d] = rne16(o);
    sum += o;
    vv[pp] = qkvb[(size_t)s * NQKV + (H + HL) * D + hl * D + d];  // already bf16
  }
  krep[((size_t)t * HL + hl) * D + d] = sum * 0.125f;
  uint4 pk;
  pk.x = vv[0] | ((u32)vv[1] << 16);
  pk.y = vv[2] | ((u32)vv[3] << 16);
  pk.z = vv[4] | ((u32)vv[5] << 16);
  pk.w = vv[6] | ((u32)vv[7] << 16);
  *(uint4*)(vbt + ((size_t)hl * D + d) * S + t * 8) = pk;
}

// ---------------- scores + top-100 selection per head -----------------------
__global__ __launch_bounds__(512) void topk_kernel(
    const float* __restrict__ M1, const float* __restrict__ M2,
    const float* __restrict__ krep, int* __restrict__ bidx) {
  const int h = blockIdx.x;
  const int t = threadIdx.x;  // block id 0..511
  __shared__ float qm[128];
  if (t < 128) {
    int r = h * 128 + t;
    float v = (t & 1) ? (M1[r] + M2[r - 1]) : (M1[r] - M2[r + 1]);
    qm[t] = v * (1.f / 4096.f);
  }
  __syncthreads();
  const float* kr = krep + ((size_t)t * HL + (h >> 2)) * 128;
  float s = 0.f;
#pragma unroll 8
  for (int d = 0; d < 128; ++d) s += qm[d] * kr[d];
  s *= SCALE;
  if (t < 4 || t >= 508) s = NEGF;  // sink + window masked out of top-k
  if (t < 4) {
    bidx[h * KL + t] = t;            // sink blocks 0..3
    bidx[h * KL + 4 + t] = 508 + t;  // window blocks 508..511
  }
  __shared__ float wv[8];
  __shared__ int wi[8];
  __shared__ int bestsh;
  for (int iter = 0; iter < 100; ++iter) {
    float v = s;
    int idx = t;
#pragma unroll
    for (int off = 1; off < 64; off <<= 1) {
      float ov = __shfl_xor(v, off, 64);
      int oi = __shfl_xor(idx, off, 64);
      if (ov > v || (ov == v && oi < idx)) { v = ov; idx = oi; }
    }
    if ((t & 63) == 0) { wv[t >> 6] = v; wi[t >> 6] = idx; }
    __syncthreads();
    if (t == 0) {
      float bv = wv[0];
      int bi = wi[0];
#pragma unroll
      for (int u = 1; u < 8; ++u)
        if (wv[u] > bv || (wv[u] == bv && wi[u] < bi)) { bv = wv[u]; bi = wi[u]; }
      bestsh = bi;
      bidx[h * KL + 8 + iter] = bi;
    }
    __syncthreads();
    if (t == bestsh) s = NEGF;
  }
}

// ---------------- MFMA flash attention over selected blocks -----------------
// grid (S/64, H); 256 thr = 4 waves; wave w owns q rows q0+w*16..+15.
// Per step: 4 selected blocks = 32 tokens. QK: 2 tiles x 4 K-chunks MFMA;
// online softmax in C-layout; P relayout via per-wave LDS; PV: 8 MFMA (K=32).
__global__ __launch_bounds__(256) void attn_mfma(
    const u16* __restrict__ qb, const u16* __restrict__ kb,
    const u16* __restrict__ vbt, const int* __restrict__ bidx,
    u16* __restrict__ attno) {
  __shared__ u16 Ks[32][136];   // 32 toks x 128 d (+8 pad)
  __shared__ u16 Vt[128][40];   // 128 d x 32 toks (+8 pad)
  __shared__ u16 Ps[4][16][40]; // per wave: 16 rows x 32 toks (+8 pad)
  const int h = blockIdx.y, hl = h >> 2;
  const int q0 = blockIdx.x * 64;
  const int tid = threadIdx.x;
  const int w = tid >> 6, lane = tid & 63;
  const int l15 = lane & 15, g = lane >> 4;

  bf16x8 qf[4];
  {
    const u16* qp = qb + ((size_t)h * S + q0 + w * 16 + l15) * D + g * 8;
#pragma unroll
    for (int c = 0; c < 4; ++c) qf[c] = *(const bf16x8*)(qp + c * 32);
  }
  f32x4 o[8];
#pragma unroll
  for (int c = 0; c < 8; ++c) o[c] = {0.f, 0.f, 0.f, 0.f};
  float mrow[4], lrow[4];
#pragma unroll
  for (int r = 0; r < 4; ++r) { mrow[r] = NEGF; lrow[r] = 0.f; }

  for (int step = 0; step < KL / 4; ++step) {
    const int b0 = bidx[h * KL + step * 4 + 0];
    const int b1 = bidx[h * KL + step * 4 + 1];
    const int b2 = bidx[h * KL + step * 4 + 2];
    const int b3 = bidx[h * KL + step * 4 + 3];
    {  // stage K: tok = tid>>3, seg = tid&7 (32B contiguous per thread)
      const int tok = tid >> 3, seg = tid & 7;
      const int blk = (tok < 8) ? b0 : (tok < 16) ? b1 : (tok < 24) ? b2 : b3;
      const u16* src = kb + ((size_t)hl * S + blk * 8 + (tok & 7)) * D + seg * 16;
      *(uint4*)&Ks[tok][seg * 16] = *(const uint4*)src;
      *(uint4*)&Ks[tok][seg * 16 + 8] = *(const uint4*)(src + 8);
    }
    {  // stage V^T: d = tid>>1, half = tid&1 (two 8-token runs)
      const int d = tid >> 1, hf = tid & 1;
      const int ba = hf ? b2 : b0, bb = hf ? b3 : b1;
      const u16* src = vbt + ((size_t)hl * D + d) * S;
      *(uint4*)&Vt[d][hf * 16] = *(const uint4*)(src + ba * 8);
      *(uint4*)&Vt[d][hf * 16 + 8] = *(const uint4*)(src + bb * 8);
    }
    __syncthreads();
    // QK^T: two 16x16 tiles (toks 0..15, 16..31)
    f32x4 sA = {0.f, 0.f, 0.f, 0.f}, sB = {0.f, 0.f, 0.f, 0.f};
#pragma unroll
    for (int c = 0; c < 4; ++c) {
      bf16x8 k0 = *(const bf16x8*)&Ks[l15][c * 32 + g * 8];
      bf16x8 k1 = *(const bf16x8*)&Ks[16 + l15][c * 32 + g * 8];
      sA = __builtin_amdgcn_mfma_f32_16x16x32_bf16(qf[c], k0, sA, 0, 0, 0);
      sB = __builtin_amdgcn_mfma_f32_16x16x32_bf16(qf[c], k1, sB, 0, 0, 0);
    }
    const int tgA = ((l15 < 8) ? b0 : b1) * 8 + (l15 & 7);
    const int tgB = ((l15 < 8) ? b2 : b3) * 8 + (l15 & 7);
    float pA[4], pB[4], alpha[4];
#pragma unroll
    for (int r = 0; r < 4; ++r) {
      const int sq = q0 + w * 16 + g * 4 + r;
      pA[r] = (tgA <= sq) ? sA[r] * SCALE : NEGF;
      pB[r] = (tgB <= sq) ? sB[r] * SCALE : NEGF;
      float mx = fmaxf(pA[r], pB[r]);
      mx = fmaxf(mx, __shfl_xor(mx, 1, 64));
      mx = fmaxf(mx, __shfl_xor(mx, 2, 64));
      mx = fmaxf(mx, __shfl_xor(mx, 4, 64));
      mx = fmaxf(mx, __shfl_xor(mx, 8, 64));
      const float mnew = fmaxf(mrow[r], mx);
      alpha[r] = __expf(mrow[r] - mnew);
      mrow[r] = mnew;
      pA[r] = __expf(pA[r] - mnew);
      pB[r] = __expf(pB[r] - mnew);
      float rs = pA[r] + pB[r];
      rs += __shfl_xor(rs, 1, 64);
      rs += __shfl_xor(rs, 2, 64);
      rs += __shfl_xor(rs, 4, 64);
      rs += __shfl_xor(rs, 8, 64);
      lrow[r] = lrow[r] * alpha[r] + rs;
    }
#pragma unroll
    for (int c = 0; c < 8; ++c) {
      o[c][0] *= alpha[0]; o[c][1] *= alpha[1];
      o[c][2] *= alpha[2]; o[c][3] *= alpha[3];
    }
    // P: C-layout -> LDS -> A-layout (within-wave, in-order LDS)
#pragma unroll
    for (int r = 0; r < 4; ++r) {
      Ps[w][g * 4 + r][l15] = rne16(pA[r]);
      Ps[w][g * 4 + r][16 + l15] = rne16(pB[r]);
    }
    bf16x8 pf = *(const bf16x8*)&Ps[w][l15][g * 8];
#pragma unroll
    for (int c = 0; c < 8; ++c) {
      bf16x8 vf = *(const bf16x8*)&Vt[c * 16 + l15][g * 8];
      o[c] = __builtin_amdgcn_mfma_f32_16x16x32_bf16(pf, vf, o[c], 0, 0, 0);
    }
    __syncthreads();
  }
  float inv[4];
#pragma unroll
  for (int r = 0; r < 4; ++r) inv[r] = 1.f / lrow[r];
#pragma unroll
  for (int c = 0; c < 8; ++c)
#pragma unroll
    for (int r = 0; r < 4; ++r)
      attno[(size_t)(q0 + w * 16 + g * 4 + r) * DIM + h * D + c * 16 + l15] =
          rne16(o[c][r] * inv[r]);
}

extern "C" void kernel_launch(void* const* d_in, const int* in_sizes, int n_in,
                              void* d_out, int out_size, void* d_ws, size_t ws_size,
                              hipStream_t stream) {
  const float* x     = (const float*)d_in[0];  // (1,4096,4096)
  const float* freqs = (const float*)d_in[1];  // (4096,64,2)
  const float* wqkv  = (const float*)d_in[2];  // (6144,4096)
  const float* wo    = (const float*)d_in[3];  // (4096,4096)
  float* out = (float*)d_out;                  // (1,4096,4096) f32

  char* p = (char*)d_ws;
  auto alloc = [&](size_t bytes) {
    char* r = p;
    p += (bytes + 255) & ~(size_t)255;
    return r;
  };
  u16*   qkvb = (u16*)alloc((size_t)S * NQKV * 2);     // 48 MB bf16 qkv
  float* kf32 = (float*)alloc((size_t)S * HL * D * 4); // 16 MB precise k
  u16*   qb   = (u16*)alloc((size_t)H * S * D * 2);    // 32 MB (H,S,D)
  u16*   kb   = (u16*)alloc((size_t)HL * S * D * 2);   // 8 MB (HL,S,D)
  u16*   vbt  = (u16*)alloc((size_t)HL * D * S * 2);   // 8 MB (HL,D,S)
  float* krep = (float*)alloc((size_t)TB * HL * D * 4);// 2 MB
  float* XC   = (float*)alloc((size_t)64 * DIM * 4);   // 1 MB
  float* XD   = (float*)alloc((size_t)64 * DIM * 4);   // 1 MB
  float* M1   = (float*)alloc((size_t)H * D * 4);
  float* M2   = (float*)alloc((size_t)H * D * 4);
  int*   bidx = (int*)alloc((size_t)H * KL * 4);
  u16*   attno = (u16*)alloc((size_t)S * DIM * 2);     // 32 MB

  hipMemsetAsync(XC, 0, (size_t)64 * DIM * 4, stream);
  hipMemsetAsync(XD, 0, (size_t)64 * DIM * 4, stream);

  // bf16 qkv (attention inputs)
  gemm_conv<false, true><<<dim3(NQKV / 128, S / 128), 256, 0, stream>>>(
      x, wqkv, qkvb, S, NQKV, DIM);
  // precise K heads (selection path)
  gemm_split3<<<dim3(1024 / 128, S / 128), 256, 0, stream>>>(
      x, wqkv + (size_t)H * D * DIM, kf32, S, HL * D, DIM);
  // exact q_mean via rope linearity
  xcd_kernel<<<dim3(32, 2, 8), 128, 0, stream>>>(x, freqs, XC, XD);
  mrow_kernel<<<1024, 256, 0, stream>>>(wqkv, XC, XD, M1, M2);
  rope_q_kernel<<<dim3(S / 64, H), 256, 0, stream>>>(qkvb, freqs, qb);
  rope_kv_kernel<<<dim3(TB, HL), 128, 0, stream>>>(kf32, qkvb, freqs, kb, vbt, krep);
  topk_kernel<<<H, 512, 0, stream>>>(M1, M2, krep, bidx);
  attn_mfma<<<dim3(S / 64, H), 256, 0, stream>>>(qb, kb, vbt, bidx, attno);
  gemm_conv<true, false><<<dim3(DIM / 128, S / 128), 256, 0, stream>>>(
      attno, wo, out, S, DIM, DIM);
}